// Round 1
// 168.280 us; speedup vs baseline: 1.0876x; 1.0876x over previous
//
#include <hip/hip_runtime.h>
#include <hip/hip_bf16.h>

// Problem constants
#define BATCH 2
#define LSEQ 2048
#define DMODEL 1024
#define NH 16
#define DQK 16
#define DV 64
#define FDIM 273            // 1 + 16 + 256
#define CHUNK 128
#define NCH (LSEQ / CHUNK)  // 16 chunks per batch row
#define ROWS (BATCH * LSEQ) // 4096
#define NBH (BATCH * NH)    // 32
#define NBC (NBH * NCH)     // 512 (b,h,chunk) units
#define QKVW 1536           // fused qkv row stride (bf16)
#define C2 0.17677669529663687f  // 1/(4*sqrt(2))

typedef short bf16x8 __attribute__((ext_vector_type(8)));
typedef float f32x4 __attribute__((ext_vector_type(4)));

__device__ __forceinline__ unsigned short f2bf(float f) {
  __hip_bfloat16 h = __float2bfloat16(f);
  unsigned short u; __builtin_memcpy(&u, &h, 2); return u;
}
__device__ __forceinline__ float bf2f(unsigned short u) {
  unsigned int v = (unsigned int)u << 16; float f; __builtin_memcpy(&f, &v, 4); return f;
}

__device__ __forceinline__ void storeC(float* C, size_t off, float v) { C[off] = v; }
__device__ __forceinline__ void storeC(unsigned short* C, size_t off, float v) {
  C[off] = f2bf(v);
}

// ---------------------------------------------------------------------------
// prep: z=0..3 -> W (KxN fp32) transpose+cast to Wt (NxK bf16);
//       z=4    -> hs fp32 -> bf16 cast.
// wqt/wkt/wvt land contiguously -> combined 1536x1024 QKV weight.
// ---------------------------------------------------------------------------
__global__ __launch_bounds__(256) void prep(
    const float* __restrict__ hs,
    const float* __restrict__ Wq, const float* __restrict__ Wk,
    const float* __restrict__ Wv, const float* __restrict__ Wo,
    unsigned short* __restrict__ hsb,
    unsigned short* __restrict__ wqt, unsigned short* __restrict__ wkt,
    unsigned short* __restrict__ wvt, unsigned short* __restrict__ wot) {
  __shared__ float t[32][33];
  if (blockIdx.z == 4) {
    int bid = blockIdx.y * 32 + blockIdx.x;
    const float4* in4 = (const float4*)hs;
#pragma unroll
    for (int k = 0; k < 4; k++) {
      int i = bid * 1024 + k * 256 + threadIdx.x;
      float4 v = in4[i];
      ushort4 o = {f2bf(v.x), f2bf(v.y), f2bf(v.z), f2bf(v.w)};
      ((ushort4*)hsb)[i] = o;
    }
    return;
  }
  const float* W; unsigned short* Wt; int N;
  switch (blockIdx.z) {
    case 0: W = Wq; Wt = wqt; N = 256; break;
    case 1: W = Wk; Wt = wkt; N = 256; break;
    case 2: W = Wv; Wt = wvt; N = 1024; break;
    default: W = Wo; Wt = wot; N = 1024; break;
  }
  const int nb = blockIdx.x * 32;
  if (nb >= N) return;
  const int kb = blockIdx.y * 32;
  const int tx = threadIdx.x & 31, ty4 = (threadIdx.x >> 5) * 4;
#pragma unroll
  for (int r = 0; r < 4; r++)
    t[ty4 + r][tx] = W[(size_t)(kb + ty4 + r) * N + nb + tx];
  __syncthreads();
#pragma unroll
  for (int r = 0; r < 4; r++)
    Wt[(size_t)(nb + ty4 + r) * DMODEL + kb + tx] = f2bf(t[tx][ty4 + r]);
}

// ---------------------------------------------------------------------------
// MFMA GEMM, BM=128 x BN=128 tile, BK=32, 256 threads = 4 waves,
// each wave a 64x64 quadrant (4x4 acc).
// Depth-3 software pipeline: 4-buffer LDS ring (4 x 16 KB), global_load_lds
// issued 3 K-steps ahead, counted s_waitcnt vmcnt(12) + RAW s_barrier
// (never drains vmcnt to 0 in the main loop -- T3/T4 pattern).
// Ring hazard: stage t+3 writes buf[(t-1)&3]; safe because barrier B of
// iter t-1 guarantees all waves finished reading it (ds_reads retire
// before MFMA issue via compiler lgkmcnt).
// ---------------------------------------------------------------------------
template <typename CT>
__global__ __launch_bounds__(256) void gemm_pipe(
    const unsigned short* __restrict__ A, const unsigned short* __restrict__ Bt,
    CT* __restrict__ C, int M, int N, int K) {
  __shared__ unsigned short Sbuf[4 * 8192];  // 4 stages x (A 8KB | B 8KB)
  const int tid = threadIdx.x;
  const int bm = blockIdx.y * 128, bn = blockIdx.x * 128;
  const int lane = tid & 63;
  const int w = tid >> 6;
  const int qr = (w >> 1) * 64, qc = (w & 1) * 64;
  const int nk = K >> 5;
  f32x4 acc[4][4] = {};

  // stage K-step t into ring buffer (4 x global_load_lds dwordx4 per thread)
  auto stage = [&](int t) {
    const int k0 = t << 5;
    unsigned short* Sb = Sbuf + (size_t)(t & 3) * 8192;
#pragma unroll
    for (int j = 0; j < 4; ++j) {
      int c = j * 256 + tid;        // 0..1023; wave-aligned A/B split
      int isB = c >> 9;
      int cc = c & 511;
      int row = ((cc >> 6) << 4) + (cc & 15);
      int kh = (cc >> 4) & 3;
      const unsigned short* gp =
          (isB ? Bt + (size_t)(bn + row) * K : A + (size_t)(bm + row) * K) + k0 + kh * 8;
      unsigned short* lp = Sb + isB * 4096 + cc * 8;
      __builtin_amdgcn_global_load_lds(
          (const __attribute__((address_space(1))) unsigned int*)(const void*)gp,
          (__attribute__((address_space(3))) unsigned int*)lp, 16, 0, 0);
    }
  };

  // prologue: fill 3 stages (12 loads/thread in flight)
#pragma unroll
  for (int t = 0; t < 3; ++t)
    if (t < nk) stage(t);

  for (int t = 0; t < nk; ++t) {
    if (t + 3 < nk) stage(t + 3);
    // counted wait: leave future stages' loads in flight across the barrier
    if      (t + 3 < nk) asm volatile("s_waitcnt vmcnt(12)" ::: "memory");
    else if (t + 2 < nk) asm volatile("s_waitcnt vmcnt(8)" ::: "memory");
    else if (t + 1 < nk) asm volatile("s_waitcnt vmcnt(4)" ::: "memory");
    else                 asm volatile("s_waitcnt vmcnt(0)" ::: "memory");
    __builtin_amdgcn_s_barrier();  // barrier A: stage t fully landed (all waves)

    const unsigned short* Ab = Sbuf + (size_t)(t & 3) * 8192;
    const unsigned short* Bb = Ab + 4096;
    bf16x8 a[4], b[4];
#pragma unroll
    for (int i = 0; i < 4; ++i)
      a[i] = *(const bf16x8*)(Ab + ((qr >> 4) + i) * 512 + lane * 8);
#pragma unroll
    for (int i = 0; i < 4; ++i)
      b[i] = *(const bf16x8*)(Bb + ((qc >> 4) + i) * 512 + lane * 8);
#pragma unroll
    for (int i = 0; i < 4; ++i)
#pragma unroll
      for (int jj = 0; jj < 4; ++jj)
        acc[i][jj] = __builtin_amdgcn_mfma_f32_16x16x32_bf16(a[i], b[jj], acc[i][jj], 0, 0, 0);

    __builtin_amdgcn_s_barrier();  // barrier B: reads of buf[t&3] done chip... block-wide
    asm volatile("" ::: "memory"); // keep next stage-issue below barrier B
  }

  const int cn = lane & 15, r0 = (lane >> 4) * 4;
#pragma unroll
  for (int i = 0; i < 4; ++i)
#pragma unroll
    for (int jj = 0; jj < 4; ++jj) {
      size_t base = (size_t)(bm + qr + i * 16 + r0) * N + bn + qc + jj * 16 + cn;
#pragma unroll
      for (int r = 0; r < 4; ++r) storeC(C, base + (size_t)r * N, acc[i][jj][r]);
    }
}

// ---------------------------------------------------------------------------
// Shared helper: stage [V | 1 | 0-pad] (B-operand fragments, N=80, K=128)
// into Vp via coalesced bf16x8 global loads + LDS scalar scatter.
// ---------------------------------------------------------------------------
__device__ __forceinline__ void stage_Vp(const unsigned short* __restrict__ qkvb,
                                         int row0, int h, int tid, short* Vp) {
  // V region: 128 rows x 64 e  ->  tiles 0..15
#pragma unroll
  for (int it = 0; it < 4; it++) {
    int t = it * 256 + tid;
    int j = t >> 3, e0 = (t & 7) * 8;
    bf16x8 v8 = *(const bf16x8*)(qkvb + (size_t)(row0 + j) * QKVW + 512 + h * 64 + e0);
    int jg = j >> 3, jj = j & 7;
#pragma unroll
    for (int u = 0; u < 8; u++) {
      int e = e0 + u;
      Vp[((e >> 4) * 4 + (jg >> 2)) * 512 + ((jg & 3) * 16 + (e & 15)) * 8 + jj] =
          v8[u];
    }
  }
  // ones/pad region: tiles 16..19 (e = 64..79)
  {
    int n = tid & 15, jgrp = tid >> 4;
    bf16x8 v8;
#pragma unroll
    for (int u = 0; u < 8; u++) v8[u] = (n == 0) ? (short)0x3F80 : (short)0;
    *(bf16x8*)(Vp + (16 + (jgrp >> 2)) * 512 + ((jgrp & 3) * 16 + n) * 8) = v8;
  }
}

// ---------------------------------------------------------------------------
// Pass 1 (MFMA): [S_c|u_c] = Kf^T[288x128] @ [V|1|pad][128x80] per (b,h,chunk),
// emitted DIRECTLY in the PG bf16 B-fragment layout (45 tiles x 512).
// ---------------------------------------------------------------------------
__global__ __launch_bounds__(256) void chunk_sums_mfma(
    const unsigned short* __restrict__ qkvb, unsigned short* __restrict__ Sfrag) {
  const int c = blockIdx.x, bh = blockIdx.y;
  const int b = bh >> 4, h = bh & 15;
  const int tid = threadIdx.x;
  const int lane = tid & 63, w = tid >> 6;
  const int row0 = b * LSEQ + c * CHUNK;

  __shared__ float ksT[16 * 132];   // k transposed [d][i], stride 132
  __shared__ short SH[56 * 512];    // Vp[0..20*512) | Kf0 | Kf1 ; epi: Sfrag stage
  short* Vp = SH;
  short* Kf0 = SH + 20 * 512;
  short* Kf1 = SH + 38 * 512;

  // ---- stage ksT (fp32 from bf16 k; stride 132 -> 2-way-free banks) ----
  {
    int i = tid >> 1, d0 = (tid & 1) * 8;
    bf16x8 k8 = *(const bf16x8*)(qkvb + (size_t)(row0 + i) * QKVW + 256 + h * 16 + d0);
#pragma unroll
    for (int j = 0; j < 8; j++) ksT[(d0 + j) * 132 + i] = bf2f((unsigned short)k8[j]);
  }
  stage_Vp(qkvb, row0, h, tid, Vp);
  __syncthreads();

  // ---- kf-slice generator: rows i0..i0+31 of Kf^T into Kf buf ----
  auto gen = [&](int kt, short* dst) {
    for (int o = tid; o < 1152; o += 256) {
      int mt = o >> 6, w6 = o & 63;
      int kh = w6 >> 4, m = w6 & 15;
      int f = mt * 16 + m;
      int i0 = kt * 32 + kh * 8;
      bf16x8 v8;
      if (f == 0) {
#pragma unroll
        for (int j = 0; j < 8; j++) v8[j] = (short)0x3F80;
      } else if (f < 17) {
        const float* ka = &ksT[(f - 1) * 132 + i0];
        float4 a0 = *(const float4*)ka, a1 = *(const float4*)(ka + 4);
        v8[0] = (short)f2bf(0.5f * a0.x); v8[1] = (short)f2bf(0.5f * a0.y);
        v8[2] = (short)f2bf(0.5f * a0.z); v8[3] = (short)f2bf(0.5f * a0.w);
        v8[4] = (short)f2bf(0.5f * a1.x); v8[5] = (short)f2bf(0.5f * a1.y);
        v8[6] = (short)f2bf(0.5f * a1.z); v8[7] = (short)f2bf(0.5f * a1.w);
      } else if (f < FDIM) {
        int ix = f - 17;
        const float* ka = &ksT[(ix >> 4) * 132 + i0];
        const float* kb2 = &ksT[(ix & 15) * 132 + i0];
        float4 a0 = *(const float4*)ka, a1 = *(const float4*)(ka + 4);
        float4 b0 = *(const float4*)kb2, b1 = *(const float4*)(kb2 + 4);
        v8[0] = (short)f2bf(C2 * a0.x * b0.x); v8[1] = (short)f2bf(C2 * a0.y * b0.y);
        v8[2] = (short)f2bf(C2 * a0.z * b0.z); v8[3] = (short)f2bf(C2 * a0.w * b0.w);
        v8[4] = (short)f2bf(C2 * a1.x * b1.x); v8[5] = (short)f2bf(C2 * a1.y * b1.y);
        v8[6] = (short)f2bf(C2 * a1.z * b1.z); v8[7] = (short)f2bf(C2 * a1.w * b1.w);
      } else {
#pragma unroll
        for (int j = 0; j < 8; j++) v8[j] = 0;
      }
      *(bf16x8*)(dst + mt * 512 + (kh * 16 + m) * 8) = v8;
    }
  };

  gen(0, Kf0);
  __syncthreads();

  f32x4 acc[5][5] = {};
  const int nmt = (w < 2) ? 5 : 4;
  for (int kt = 0; kt < 4; kt++) {
    short* cur = (kt & 1) ? Kf1 : Kf0;
    if (kt < 3) gen(kt + 1, (kt & 1) ? Kf0 : Kf1);
    bf16x8 bv[5];
#pragma unroll
    for (int nt = 0; nt < 5; nt++)
      bv[nt] = *(const bf16x8*)(Vp + (nt * 4 + kt) * 512 + lane * 8);
#pragma unroll
    for (int t2 = 0; t2 < 5; t2++) {
      if (t2 < nmt) {  // wave-uniform; keeps acc indices compile-time (R5 lesson)
        int mt = w + t2 * 4;
        bf16x8 av = *(const bf16x8*)(cur + mt * 512 + lane * 8);
#pragma unroll
        for (int nt = 0; nt < 5; nt++)
          acc[t2][nt] = __builtin_amdgcn_mfma_f32_16x16x32_bf16(av, bv[nt], acc[t2][nt], 0, 0, 0);
      }
    }
    __syncthreads();
  }

  // ---- epilogue: scatter acc -> SH in fragment layout, then bulk store ----
  const int cl = lane & 15, r0q = (lane >> 4) * 4;
#pragma unroll
  for (int t2 = 0; t2 < 5; t2++) {
    if (t2 < nmt) {
      int mt = w + t2 * 4;
#pragma unroll
      for (int reg = 0; reg < 4; reg++) {
        int f = mt * 16 + r0q + reg;  // 0..287; f>=FDIM values are exact 0
#pragma unroll
        for (int nt = 0; nt < 5; nt++) {
          int e = nt * 16 + cl;       // 0..79; e>64 values are exact 0
          SH[((f >> 5) * 5 + nt) * 512 + (((f >> 3) & 3) * 16 + (e & 15)) * 8 + (f & 7)] =
              (short)f2bf(acc[t2][nt][reg]);
        }
      }
    }
  }
  __syncthreads();
  unsigned short* dst = Sfrag + ((size_t)bh * NCH + c) * 45 * 512;
  for (int o = tid; o < 2880; o += 256)
    *(bf16x8*)(dst + o * 8) = *(const bf16x8*)(SH + o * 8);
}

// ---------------------------------------------------------------------------
// Pass 2: exclusive prefix over chunks in fragment layout, fully vectorized.
// ---------------------------------------------------------------------------
__global__ __launch_bounds__(64) void prefix_scan_frag(
    const unsigned short* __restrict__ Sfrag, unsigned short* __restrict__ PG) {
  const int kt5 = blockIdx.x, bh = blockIdx.y;
  const int lane = threadIdx.x;
  float run[8] = {0.f, 0.f, 0.f, 0.f, 0.f, 0.f, 0.f, 0.f};
  const size_t base = ((size_t)bh * NCH * 45 + kt5) * 512 + lane * 8;
#pragma unroll
  for (int cc = 0; cc < NCH; cc++) {
    size_t a = base + (size_t)cc * 45 * 512;
    bf16x8 s8 = *(const bf16x8*)(Sfrag + a);
    bf16x8 o8;
#pragma unroll
    for (int j = 0; j < 8; j++) {
      o8[j] = (short)f2bf(run[j]);
      run[j] += bf2f((unsigned short)s8[j]);
    }
    *(bf16x8*)(PG + a) = o8;
  }
}

// ---------------------------------------------------------------------------
// Pass 3 (MFMA): per-(b,h,chunk) outputs -> bf16 y.
// LDS union U (73.7 KB, 2 blocks/CU):
//   phase 1: Qb U[0..4095], Kb U[4096..8191]; epi-> Am U[8192..24575]
//   phase 2: Vp U[24576..34815]
//   Qf gen : full 128x288 Qf A-fragments -> U[0..36863] (once, q in VGPRs)
//   phase 3: barrier-free; B-fragments loaded straight from PG (lane*16B).
// ---------------------------------------------------------------------------
__global__ __launch_bounds__(256) void attn_mfma(
    const unsigned short* __restrict__ qkvb, const unsigned short* __restrict__ PG,
    unsigned short* __restrict__ ybuf) {
  const int c = blockIdx.x, bh = blockIdx.y;
  const int b = bh >> 4, h = bh & 15;
  const int tid = threadIdx.x;
  const int lane = tid & 63, w = tid >> 6;
  const int row0 = b * LSEQ + c * CHUNK;

  __shared__ short U[36864];
  __shared__ float denL[128];
  unsigned short* Uu = (unsigned short*)U;

  // ---- issue q-row global loads early (held in VGPRs for Qf gen) ----
  const int qrow = (w >> 1) * 64 + lane;  // 0..127 (wave-uniform halves)
  const int shalf = w & 1;                // wave-uniform feature-half selector
  bf16x8 qa = *(const bf16x8*)(qkvb + (size_t)(row0 + qrow) * QKVW + h * 16);
  bf16x8 qb = *(const bf16x8*)(qkvb + (size_t)(row0 + qrow) * QKVW + h * 16 + 8);

  // ---- stage Qb, Kb (bf16 fragments, K padded to 32 with zeros) ----
  for (int t = tid; t < 1024; t += 256) {
    int isK = t >> 9;
    int tt = t & 511;
    int i = tt >> 2, kh = tt & 3;
    bf16x8 v8 = {0, 0, 0, 0, 0, 0, 0, 0};
    if (kh < 2)
      v8 = *(const bf16x8*)(qkvb + (size_t)(row0 + i) * QKVW + isK * 256 + h * 16 + kh * 8);
    *(bf16x8*)(U + isK * 4096 + (i >> 4) * 512 + (kh * 16 + (i & 15)) * 8) = v8;
  }
  __syncthreads();

  // ---- phase 1: S = Q K^T -> poly+mask -> Am (disjoint regions, no mid-sync)
  {
    bf16x8 aq[2];
#pragma unroll
    for (int mi = 0; mi < 2; mi++)
      aq[mi] = *(const bf16x8*)(U + (w * 2 + mi) * 512 + lane * 8);
    f32x4 S[2][8] = {};
#pragma unroll
    for (int nt = 0; nt < 8; nt++) {
      bf16x8 bk = *(const bf16x8*)(U + 4096 + nt * 512 + lane * 8);
#pragma unroll
      for (int mi = 0; mi < 2; mi++)
        S[mi][nt] = __builtin_amdgcn_mfma_f32_16x16x32_bf16(aq[mi], bk, S[mi][nt], 0, 0, 0);
    }
    const int cl = lane & 15, r0q = (lane >> 4) * 4;
#pragma unroll
    for (int mi = 0; mi < 2; mi++)
#pragma unroll
      for (int nt = 0; nt < 8; nt++)
#pragma unroll
        for (int reg = 0; reg < 4; reg++) {
          int i = (w * 2 + mi) * 16 + r0q + reg;
          int j = nt * 16 + cl;
          float s = S[mi][nt][reg];
          float aij = (j <= i) ? fmaf(s, fmaf(s, 0.03125f, 0.25f), 1.0f) : 0.0f;
          U[8192 + ((i >> 4) * 4 + (j >> 5)) * 512 +
            (((j >> 3) & 3) * 16 + (i & 15)) * 8 + (j & 7)] = (short)f2bf(aij);
        }
  }
  // ---- stage Vp (coalesced loads + LDS scatter) ----
  stage_Vp(qkvb, row0, h, tid, U + 24576);
  __syncthreads();

  // ---- phase 2: Y = A · Vp ----
  f32x4 Y[2][5] = {};
#pragma unroll
  for (int kc = 0; kc < 4; kc++) {
    bf16x8 a2[2];
#pragma unroll
    for (int mi = 0; mi < 2; mi++)
      a2[mi] = *(const bf16x8*)(U + 8192 + ((w * 2 + mi) * 4 + kc) * 512 + lane * 8);
#pragma unroll
    for (int nt = 0; nt < 5; nt++) {
      bf16x8 b2 = *(const bf16x8*)(U + 24576 + (nt * 4 + kc) * 512 + lane * 8);
#pragma unroll
      for (int mi = 0; mi < 2; mi++)
        Y[mi][nt] = __builtin_amdgcn_mfma_f32_16x16x32_bf16(a2[mi], b2, Y[mi][nt], 0, 0, 0);
    }
  }
  __syncthreads();  // phase-2 reads done; U[0..36863] free for Qf

  // ---- Qf gen: thread-owns-row, q in VGPRs, one mul per feature ----
  {
    float qv[16], cq[16];
#pragma unroll
    for (int j = 0; j < 8; j++) {
      qv[j] = bf2f((unsigned short)qa[j]);
      qv[8 + j] = bf2f((unsigned short)qb[j]);
    }
#pragma unroll
    for (int j = 0; j < 16; j++) cq[j] = C2 * qv[j];
    unsigned short* qbase = Uu + (qrow >> 4) * 512 + (qrow & 15) * 8;
    if (shalf == 0) {
#pragma unroll
      for (int vk = 0; vk < 18; vk++) {
        bf16x8 v8;
#pragma unroll
        for (int j = 0; j < 8; j++) {
          int f = vk * 8 + j;
          float qf;
          if (f == 0) qf = 1.0f;
          else if (f < 17) qf = 0.5f * qv[f - 1];
          else { int ix = f - 17; qf = cq[ix >> 4] * qv[ix & 15]; }
          v8[j] = (short)f2bf(qf);
        }
        *(bf16x8*)(qbase + (vk >> 2) * 4096 + (vk & 3) * 128) = v8;
      }
    } else {
#pragma unroll
      for (int vk = 18; vk < 36; vk++) {
        bf16x8 v8;
#pragma unroll
        for (int j = 0; j < 8; j++) {
          int f = vk * 8 + j;
          float qf;
          if (f < FDIM) { int ix = f - 17; qf = cq[ix >> 4] * qv[ix & 15]; }
          else qf = 0.0f;
          v8[j] = (short)f2bf(qf);
        }
        *(bf16x8*)(qbase + (vk >> 2) * 4096 + (vk & 3) * 128) = v8;
      }
    }
  }
  __syncthreads();  // Qf complete; phase 3 is barrier-free from here

  // ---- phase 3: Y += Qf · [P|u]; B-fragments DIRECT from global PG ----
  const unsigned short* pgl = PG + ((size_t)bh * NCH + c) * 45 * 512 + lane * 8;
#pragma unroll
  for (int ft = 0; ft < 9; ft++) {
    bf16x8 b3[5];
#pragma unroll
    for (int nt = 0; nt < 5; nt++)
      b3[nt] = *(const bf16x8*)(pgl + (ft * 5 + nt) * 512);
    bf16x8 a3[2];
#pragma unroll
    for (int mi = 0; mi < 2; mi++)
      a3[mi] = *(const bf16x8*)(U + ft * 4096 + (w * 2 + mi) * 512 + lane * 8);
#pragma unroll
    for (int nt = 0; nt < 5; nt++)
#pragma unroll
      for (int mi = 0; mi < 2; mi++)
        Y[mi][nt] = __builtin_amdgcn_mfma_f32_16x16x32_bf16(a3[mi], b3[nt], Y[mi][nt], 0, 0, 0);
  }

  // ---- epilogue: den from ones column (nt=4, col 0), scale, store bf16 ----
  const int cl = lane & 15, r0q = (lane >> 4) * 4;
  if (cl == 0) {
#pragma unroll
    for (int mi = 0; mi < 2; mi++)
#pragma unroll
      for (int reg = 0; reg < 4; reg++)
        denL[(w * 2 + mi) * 16 + r0q + reg] = Y[mi][4][reg];
  }
  __syncthreads();
#pragma unroll
  for (int mi = 0; mi < 2; mi++) {
    float invd[4];
#pragma unroll
    for (int reg = 0; reg < 4; reg++)
      invd[reg] = 1.0f / (denL[(w * 2 + mi) * 16 + r0q + reg] + 1e-12f);
#pragma unroll
    for (int nt = 0; nt < 4; nt++)
#pragma unroll
      for (int reg = 0; reg < 4; reg++) {
        int i = (w * 2 + mi) * 16 + r0q + reg;
        int e = nt * 16 + cl;
        ybuf[(size_t)(row0 + i) * (NH * DV) + h * DV + e] =
            f2bf(Y[mi][nt][reg] * invd[reg]);
      }
  }
}

// ---------------------------------------------------------------------------
extern "C" void kernel_launch(void* const* d_in, const int* in_sizes, int n_in,
                              void* d_out, int out_size, void* d_ws, size_t ws_size,
                              hipStream_t stream) {
  const float* hs = (const float*)d_in[0];
  const float* Wq = (const float*)d_in[1];
  const float* Wk = (const float*)d_in[2];
  const float* Wv = (const float*)d_in[3];
  const float* Wo = (const float*)d_in[4];
  float* out = (float*)d_out;

  // workspace layout (~73 MB)
  unsigned short* qkvb  = (unsigned short*)d_ws;            // 4096 x 1536 bf16 (q|k|v)
  unsigned short* Sfrag = qkvb + (size_t)ROWS * QKVW;       // 512 x 45 x 512 bf16
  unsigned short* PG    = Sfrag + (size_t)NBC * 45 * 512;   // 512 x 45 x 512 bf16
  unsigned short* hsb   = PG + (size_t)NBC * 45 * 512;      // 4096 x 1024 bf16
  unsigned short* yb    = hsb;  // alias: hsb dead after projection GEMM
  unsigned short* wqt   = hsb + (size_t)ROWS * DMODEL;      // 256 x 1024 bf16
  unsigned short* wkt   = wqt + (size_t)(NH * DQK) * DMODEL;
  unsigned short* wvt   = wkt + (size_t)(NH * DQK) * DMODEL; // contiguous -> 1536x1024
  unsigned short* wot   = wvt + (size_t)(NH * DV) * DMODEL;  // 1024 x 1024 bf16

  // fused casts + transposes (one launch)
  prep<<<dim3(32, 32, 5), 256, 0, stream>>>(hs, Wq, Wk, Wv, Wo, hsb, wqt, wkt, wvt, wot);

  // fused q|k|v projection (MFMA, bf16 out, N=1536): 384 blocks, 128^2 tile
  gemm_pipe<unsigned short><<<dim3(QKVW / 128, ROWS / 128), 256, 0, stream>>>(
      hsb, wqt, qkvb, ROWS, QKVW, DMODEL);

  // chunked causal linear attention
  chunk_sums_mfma<<<dim3(NCH, NBH), 256, 0, stream>>>(qkvb, Sfrag);
  prefix_scan_frag<<<dim3(45, NBH), 64, 0, stream>>>(Sfrag, PG);
  attn_mfma<<<dim3(NCH, NBH), 256, 0, stream>>>(qkvb, PG, yb);

  // output projection (MFMA, fp32 out): 256 blocks = 1/CU, 128^2 tile
  gemm_pipe<float><<<dim3(DMODEL / 128, ROWS / 128), 256, 0, stream>>>(
      yb, wot, out, ROWS, DMODEL, DMODEL);
}

// Round 3
// 167.806 us; speedup vs baseline: 1.0907x; 1.0028x over previous
//
#include <hip/hip_runtime.h>
#include <hip/hip_bf16.h>

// Problem constants
#define BATCH 2
#define LSEQ 2048
#define DMODEL 1024
#define NH 16
#define DQK 16
#define DV 64
#define FDIM 273            // 1 + 16 + 256
#define CHUNK 128
#define NCH (LSEQ / CHUNK)  // 16 chunks per batch row
#define ROWS (BATCH * LSEQ) // 4096
#define NBH (BATCH * NH)    // 32
#define NBC (NBH * NCH)     // 512 (b,h,chunk) units
#define QKVW 1536           // fused qkv row stride (bf16)
#define C2 0.17677669529663687f  // 1/(4*sqrt(2))

typedef short bf16x8 __attribute__((ext_vector_type(8)));
typedef float f32x4 __attribute__((ext_vector_type(4)));

__device__ __forceinline__ unsigned short f2bf(float f) {
  __hip_bfloat16 h = __float2bfloat16(f);
  unsigned short u; __builtin_memcpy(&u, &h, 2); return u;
}
__device__ __forceinline__ float bf2f(unsigned short u) {
  unsigned int v = (unsigned int)u << 16; float f; __builtin_memcpy(&f, &v, 4); return f;
}

__device__ __forceinline__ void storeC(float* C, size_t off, float v) { C[off] = v; }
__device__ __forceinline__ void storeC(unsigned short* C, size_t off, float v) {
  C[off] = f2bf(v);
}

// ---------------------------------------------------------------------------
// prep: z=0..3 -> W (KxN fp32) transpose+cast to Wt (NxK bf16);
//       z=4    -> hs fp32 -> bf16 cast.
// wqt/wkt/wvt land contiguously -> combined 1536x1024 QKV weight.
// ---------------------------------------------------------------------------
__global__ __launch_bounds__(256) void prep(
    const float* __restrict__ hs,
    const float* __restrict__ Wq, const float* __restrict__ Wk,
    const float* __restrict__ Wv, const float* __restrict__ Wo,
    unsigned short* __restrict__ hsb,
    unsigned short* __restrict__ wqt, unsigned short* __restrict__ wkt,
    unsigned short* __restrict__ wvt, unsigned short* __restrict__ wot) {
  __shared__ float t[32][33];
  if (blockIdx.z == 4) {
    int bid = blockIdx.y * 32 + blockIdx.x;
    const float4* in4 = (const float4*)hs;
#pragma unroll
    for (int k = 0; k < 4; k++) {
      int i = bid * 1024 + k * 256 + threadIdx.x;
      float4 v = in4[i];
      ushort4 o = {f2bf(v.x), f2bf(v.y), f2bf(v.z), f2bf(v.w)};
      ((ushort4*)hsb)[i] = o;
    }
    return;
  }
  const float* W; unsigned short* Wt; int N;
  switch (blockIdx.z) {
    case 0: W = Wq; Wt = wqt; N = 256; break;
    case 1: W = Wk; Wt = wkt; N = 256; break;
    case 2: W = Wv; Wt = wvt; N = 1024; break;
    default: W = Wo; Wt = wot; N = 1024; break;
  }
  const int nb = blockIdx.x * 32;
  if (nb >= N) return;
  const int kb = blockIdx.y * 32;
  const int tx = threadIdx.x & 31, ty4 = (threadIdx.x >> 5) * 4;
#pragma unroll
  for (int r = 0; r < 4; r++)
    t[ty4 + r][tx] = W[(size_t)(kb + ty4 + r) * N + nb + tx];
  __syncthreads();
#pragma unroll
  for (int r = 0; r < 4; r++)
    Wt[(size_t)(nb + ty4 + r) * DMODEL + kb + tx] = f2bf(t[tx][ty4 + r]);
}

// ---------------------------------------------------------------------------
// MFMA GEMM, BM=128 x BN=128 tile, 256 threads = 4 waves, each a 64x64
// quadrant (4x4 acc).  BK=64 per barrier phase (2 staged K-steps), 4-buffer
// 16KB LDS ring, depth-3 prefetch with counted s_waitcnt vmcnt(8) + raw
// s_barrier (T3/T4).  XCD-aware bijective block swizzle (T1; nwg%8==0 for
// both launches).  s_setprio around the MFMA cluster (T5).
// Ring hazards:
//   stage(tt+3) [pre-wait]  writes buf[(tt-1)&3]: reads finished in iter
//     tt-2's compute, sealed by its barrier B (all waves passed it).
//   stage(tt+4) [post-barB] writes buf[tt&3]: this iter's reads completed
//     before barrier B (compiler lgkmcnt before MFMA use).
//   reads of buf[tt..tt+1] guarded by vmcnt(8)+barrier A.
// ---------------------------------------------------------------------------
template <typename CT>
__global__ __launch_bounds__(256) void gemm_pipe(
    const unsigned short* __restrict__ A, const unsigned short* __restrict__ Bt,
    CT* __restrict__ C, int M, int N, int K) {
  __shared__ unsigned short Sbuf[4 * 8192];  // 4 stages x (A 8KB | B 8KB)
  const int tid = threadIdx.x;
  // XCD-aware swizzle: each XCD gets a contiguous chunk of logical ids.
  const int nwg = gridDim.x * gridDim.y;
  const int bid0 = blockIdx.y * gridDim.x + blockIdx.x;
  const int bid = (bid0 & 7) * (nwg >> 3) + (bid0 >> 3);
  const int bm = (bid / gridDim.x) * 128, bn = (bid % gridDim.x) * 128;
  const int lane = tid & 63;
  const int w = tid >> 6;
  const int qr = (w >> 1) * 64, qc = (w & 1) * 64;
  const int nk = K >> 5;  // K-steps of 32; assumed even
  f32x4 acc[4][4] = {};

  // precomputed per-thread staging addresses (k0-invariant parts)
  const unsigned short* gbase[4];
  int loff[4];
#pragma unroll
  for (int j = 0; j < 4; ++j) {
    int c = j * 256 + tid;        // 0..1023; wave-aligned A/B split
    int isB = c >> 9;
    int cc = c & 511;
    int row = ((cc >> 6) << 4) + (cc & 15);
    int kh = (cc >> 4) & 3;
    gbase[j] = (isB ? Bt + (size_t)(bn + row) * K : A + (size_t)(bm + row) * K) + kh * 8;
    loff[j] = isB * 4096 + cc * 8;
  }
  auto stage = [&](int t) {
    unsigned short* Sb = Sbuf + (size_t)(t & 3) * 8192;
#pragma unroll
    for (int j = 0; j < 4; ++j)
      __builtin_amdgcn_global_load_lds(
          (const __attribute__((address_space(1))) unsigned int*)(const void*)(gbase[j] + (t << 5)),
          (__attribute__((address_space(3))) unsigned int*)(Sb + loff[j]), 16, 0, 0);
  };

  // prologue: fill 3 stages (12 loads/thread in flight)
  stage(0); stage(1); stage(2);

  for (int tt = 0; tt < nk; tt += 2) {
    if (tt + 3 < nk) {
      stage(tt + 3);
      asm volatile("s_waitcnt vmcnt(8)" ::: "memory");   // tt, tt+1 landed
    } else {
      asm volatile("s_waitcnt vmcnt(0)" ::: "memory");   // tail drain
    }
    __builtin_amdgcn_s_barrier();  // barrier A
    asm volatile("" ::: "memory");

    const unsigned short* Ab0 = Sbuf + (size_t)(tt & 3) * 8192;
    const unsigned short* Ab1 = Sbuf + (size_t)((tt + 1) & 3) * 8192;
    bf16x8 a0[4], b0[4], a1[4], b1[4];
#pragma unroll
    for (int i = 0; i < 4; ++i) {
      a0[i] = *(const bf16x8*)(Ab0 + ((qr >> 4) + i) * 512 + lane * 8);
      b0[i] = *(const bf16x8*)(Ab0 + 4096 + ((qc >> 4) + i) * 512 + lane * 8);
      a1[i] = *(const bf16x8*)(Ab1 + ((qr >> 4) + i) * 512 + lane * 8);
      b1[i] = *(const bf16x8*)(Ab1 + 4096 + ((qc >> 4) + i) * 512 + lane * 8);
    }
    __builtin_amdgcn_s_setprio(1);
#pragma unroll
    for (int i = 0; i < 4; ++i)
#pragma unroll
      for (int jj = 0; jj < 4; ++jj)
        acc[i][jj] = __builtin_amdgcn_mfma_f32_16x16x32_bf16(a0[i], b0[jj], acc[i][jj], 0, 0, 0);
#pragma unroll
    for (int i = 0; i < 4; ++i)
#pragma unroll
      for (int jj = 0; jj < 4; ++jj)
        acc[i][jj] = __builtin_amdgcn_mfma_f32_16x16x32_bf16(a1[i], b1[jj], acc[i][jj], 0, 0, 0);
    __builtin_amdgcn_s_setprio(0);

    asm volatile("" ::: "memory");
    __builtin_amdgcn_s_barrier();  // barrier B: buf[tt&3] reads done block-wide
    asm volatile("" ::: "memory");
    if (tt + 4 < nk) stage(tt + 4);  // safe: overwrites buf[tt&3]
  }

  const int cn = lane & 15, r0 = (lane >> 4) * 4;
#pragma unroll
  for (int i = 0; i < 4; ++i)
#pragma unroll
    for (int jj = 0; jj < 4; ++jj) {
      size_t base = (size_t)(bm + qr + i * 16 + r0) * N + bn + qc + jj * 16 + cn;
#pragma unroll
      for (int r = 0; r < 4; ++r) storeC(C, base + (size_t)r * N, acc[i][jj][r]);
    }
}

// ---------------------------------------------------------------------------
// Shared helper: stage [V | 1 | 0-pad] (B-operand fragments, N=80, K=128)
// into Vp via coalesced bf16x8 global loads + LDS scalar scatter.
// ---------------------------------------------------------------------------
__device__ __forceinline__ void stage_Vp(const unsigned short* __restrict__ qkvb,
                                         int row0, int h, int tid, short* Vp) {
  // V region: 128 rows x 64 e  ->  tiles 0..15
#pragma unroll
  for (int it = 0; it < 4; it++) {
    int t = it * 256 + tid;
    int j = t >> 3, e0 = (t & 7) * 8;
    bf16x8 v8 = *(const bf16x8*)(qkvb + (size_t)(row0 + j) * QKVW + 512 + h * 64 + e0);
    int jg = j >> 3, jj = j & 7;
#pragma unroll
    for (int u = 0; u < 8; u++) {
      int e = e0 + u;
      Vp[((e >> 4) * 4 + (jg >> 2)) * 512 + ((jg & 3) * 16 + (e & 15)) * 8 + jj] =
          v8[u];
    }
  }
  // ones/pad region: tiles 16..19 (e = 64..79)
  {
    int n = tid & 15, jgrp = tid >> 4;
    bf16x8 v8;
#pragma unroll
    for (int u = 0; u < 8; u++) v8[u] = (n == 0) ? (short)0x3F80 : (short)0;
    *(bf16x8*)(Vp + (16 + (jgrp >> 2)) * 512 + ((jgrp & 3) * 16 + n) * 8) = v8;
  }
}

// ---------------------------------------------------------------------------
// Pass 1 (MFMA): [S_c|u_c] = Kf^T[288x128] @ [V|1|pad][128x80] per (b,h,chunk),
// emitted DIRECTLY in the PG bf16 B-fragment layout (45 tiles x 512).
// ---------------------------------------------------------------------------
__global__ __launch_bounds__(256) void chunk_sums_mfma(
    const unsigned short* __restrict__ qkvb, unsigned short* __restrict__ Sfrag) {
  const int c = blockIdx.x, bh = blockIdx.y;
  const int b = bh >> 4, h = bh & 15;
  const int tid = threadIdx.x;
  const int lane = tid & 63, w = tid >> 6;
  const int row0 = b * LSEQ + c * CHUNK;

  __shared__ float ksT[16 * 132];   // k transposed [d][i], stride 132
  __shared__ short SH[56 * 512];    // Vp[0..20*512) | Kf0 | Kf1 ; epi: Sfrag stage
  short* Vp = SH;
  short* Kf0 = SH + 20 * 512;
  short* Kf1 = SH + 38 * 512;

  // ---- stage ksT (fp32 from bf16 k; stride 132 -> 2-way-free banks) ----
  {
    int i = tid >> 1, d0 = (tid & 1) * 8;
    bf16x8 k8 = *(const bf16x8*)(qkvb + (size_t)(row0 + i) * QKVW + 256 + h * 16 + d0);
#pragma unroll
    for (int j = 0; j < 8; j++) ksT[(d0 + j) * 132 + i] = bf2f((unsigned short)k8[j]);
  }
  stage_Vp(qkvb, row0, h, tid, Vp);
  __syncthreads();

  // ---- kf-slice generator: rows i0..i0+31 of Kf^T into Kf buf ----
  auto gen = [&](int kt, short* dst) {
    for (int o = tid; o < 1152; o += 256) {
      int mt = o >> 6, w6 = o & 63;
      int kh = w6 >> 4, m = w6 & 15;
      int f = mt * 16 + m;
      int i0 = kt * 32 + kh * 8;
      bf16x8 v8;
      if (f == 0) {
#pragma unroll
        for (int j = 0; j < 8; j++) v8[j] = (short)0x3F80;
      } else if (f < 17) {
        const float* ka = &ksT[(f - 1) * 132 + i0];
        float4 a0 = *(const float4*)ka, a1 = *(const float4*)(ka + 4);
        v8[0] = (short)f2bf(0.5f * a0.x); v8[1] = (short)f2bf(0.5f * a0.y);
        v8[2] = (short)f2bf(0.5f * a0.z); v8[3] = (short)f2bf(0.5f * a0.w);
        v8[4] = (short)f2bf(0.5f * a1.x); v8[5] = (short)f2bf(0.5f * a1.y);
        v8[6] = (short)f2bf(0.5f * a1.z); v8[7] = (short)f2bf(0.5f * a1.w);
      } else if (f < FDIM) {
        int ix = f - 17;
        const float* ka = &ksT[(ix >> 4) * 132 + i0];
        const float* kb2 = &ksT[(ix & 15) * 132 + i0];
        float4 a0 = *(const float4*)ka, a1 = *(const float4*)(ka + 4);
        float4 b0 = *(const float4*)kb2, b1 = *(const float4*)(kb2 + 4);
        v8[0] = (short)f2bf(C2 * a0.x * b0.x); v8[1] = (short)f2bf(C2 * a0.y * b0.y);
        v8[2] = (short)f2bf(C2 * a0.z * b0.z); v8[3] = (short)f2bf(C2 * a0.w * b0.w);
        v8[4] = (short)f2bf(C2 * a1.x * b1.x); v8[5] = (short)f2bf(C2 * a1.y * b1.y);
        v8[6] = (short)f2bf(C2 * a1.z * b1.z); v8[7] = (short)f2bf(C2 * a1.w * b1.w);
      } else {
#pragma unroll
        for (int j = 0; j < 8; j++) v8[j] = 0;
      }
      *(bf16x8*)(dst + mt * 512 + (kh * 16 + m) * 8) = v8;
    }
  };

  gen(0, Kf0);
  __syncthreads();

  f32x4 acc[5][5] = {};
  const int nmt = (w < 2) ? 5 : 4;
  for (int kt = 0; kt < 4; kt++) {
    short* cur = (kt & 1) ? Kf1 : Kf0;
    if (kt < 3) gen(kt + 1, (kt & 1) ? Kf0 : Kf1);
    bf16x8 bv[5];
#pragma unroll
    for (int nt = 0; nt < 5; nt++)
      bv[nt] = *(const bf16x8*)(Vp + (nt * 4 + kt) * 512 + lane * 8);
#pragma unroll
    for (int t2 = 0; t2 < 5; t2++) {
      if (t2 < nmt) {  // wave-uniform; keeps acc indices compile-time (R5 lesson)
        int mt = w + t2 * 4;
        bf16x8 av = *(const bf16x8*)(cur + mt * 512 + lane * 8);
#pragma unroll
        for (int nt = 0; nt < 5; nt++)
          acc[t2][nt] = __builtin_amdgcn_mfma_f32_16x16x32_bf16(av, bv[nt], acc[t2][nt], 0, 0, 0);
      }
    }
    __syncthreads();
  }

  // ---- epilogue: scatter acc -> SH in fragment layout, then bulk store ----
  const int cl = lane & 15, r0q = (lane >> 4) * 4;
#pragma unroll
  for (int t2 = 0; t2 < 5; t2++) {
    if (t2 < nmt) {
      int mt = w + t2 * 4;
#pragma unroll
      for (int reg = 0; reg < 4; reg++) {
        int f = mt * 16 + r0q + reg;  // 0..287; f>=FDIM values are exact 0
#pragma unroll
        for (int nt = 0; nt < 5; nt++) {
          int e = nt * 16 + cl;       // 0..79; e>64 values are exact 0
          SH[((f >> 5) * 5 + nt) * 512 + (((f >> 3) & 3) * 16 + (e & 15)) * 8 + (f & 7)] =
              (short)f2bf(acc[t2][nt][reg]);
        }
      }
    }
  }
  __syncthreads();
  unsigned short* dst = Sfrag + ((size_t)bh * NCH + c) * 45 * 512;
  for (int o = tid; o < 2880; o += 256)
    *(bf16x8*)(dst + o * 8) = *(const bf16x8*)(SH + o * 8);
}

// ---------------------------------------------------------------------------
// Pass 2: exclusive prefix over chunks in fragment layout, fully vectorized.
// ---------------------------------------------------------------------------
__global__ __launch_bounds__(64) void prefix_scan_frag(
    const unsigned short* __restrict__ Sfrag, unsigned short* __restrict__ PG) {
  const int kt5 = blockIdx.x, bh = blockIdx.y;
  const int lane = threadIdx.x;
  float run[8] = {0.f, 0.f, 0.f, 0.f, 0.f, 0.f, 0.f, 0.f};
  const size_t base = ((size_t)bh * NCH * 45 + kt5) * 512 + lane * 8;
#pragma unroll
  for (int cc = 0; cc < NCH; cc++) {
    size_t a = base + (size_t)cc * 45 * 512;
    bf16x8 s8 = *(const bf16x8*)(Sfrag + a);
    bf16x8 o8;
#pragma unroll
    for (int j = 0; j < 8; j++) {
      o8[j] = (short)f2bf(run[j]);
      run[j] += bf2f((unsigned short)s8[j]);
    }
    *(bf16x8*)(PG + a) = o8;
  }
}

// ---------------------------------------------------------------------------
// Pass 3 (MFMA): per-(b,h,chunk) outputs -> bf16 y.
// LDS union U (73.7 KB, 2 blocks/CU):
//   phase 1: Qb U[0..4095], Kb U[4096..8191]; epi-> Am U[8192..24575]
//   phase 2: Vp U[24576..34815]
//   Qf gen : full 128x288 Qf A-fragments -> U[0..36863] (once, q in VGPRs)
//   phase 3: barrier-free; B-fragments loaded straight from PG (lane*16B).
// ---------------------------------------------------------------------------
__global__ __launch_bounds__(256) void attn_mfma(
    const unsigned short* __restrict__ qkvb, const unsigned short* __restrict__ PG,
    unsigned short* __restrict__ ybuf) {
  const int c = blockIdx.x, bh = blockIdx.y;
  const int b = bh >> 4, h = bh & 15;
  const int tid = threadIdx.x;
  const int lane = tid & 63, w = tid >> 6;
  const int row0 = b * LSEQ + c * CHUNK;

  __shared__ short U[36864];
  __shared__ float denL[128];
  unsigned short* Uu = (unsigned short*)U;

  // ---- issue q-row global loads early (held in VGPRs for Qf gen) ----
  const int qrow = (w >> 1) * 64 + lane;  // 0..127 (wave-uniform halves)
  const int shalf = w & 1;                // wave-uniform feature-half selector
  bf16x8 qa = *(const bf16x8*)(qkvb + (size_t)(row0 + qrow) * QKVW + h * 16);
  bf16x8 qb = *(const bf16x8*)(qkvb + (size_t)(row0 + qrow) * QKVW + h * 16 + 8);

  // ---- stage Qb, Kb (bf16 fragments, K padded to 32 with zeros) ----
  for (int t = tid; t < 1024; t += 256) {
    int isK = t >> 9;
    int tt = t & 511;
    int i = tt >> 2, kh = tt & 3;
    bf16x8 v8 = {0, 0, 0, 0, 0, 0, 0, 0};
    if (kh < 2)
      v8 = *(const bf16x8*)(qkvb + (size_t)(row0 + i) * QKVW + isK * 256 + h * 16 + kh * 8);
    *(bf16x8*)(U + isK * 4096 + (i >> 4) * 512 + (kh * 16 + (i & 15)) * 8) = v8;
  }
  __syncthreads();

  // ---- phase 1: S = Q K^T -> poly+mask -> Am (disjoint regions, no mid-sync)
  {
    bf16x8 aq[2];
#pragma unroll
    for (int mi = 0; mi < 2; mi++)
      aq[mi] = *(const bf16x8*)(U + (w * 2 + mi) * 512 + lane * 8);
    f32x4 S[2][8] = {};
#pragma unroll
    for (int nt = 0; nt < 8; nt++) {
      bf16x8 bk = *(const bf16x8*)(U + 4096 + nt * 512 + lane * 8);
#pragma unroll
      for (int mi = 0; mi < 2; mi++)
        S[mi][nt] = __builtin_amdgcn_mfma_f32_16x16x32_bf16(aq[mi], bk, S[mi][nt], 0, 0, 0);
    }
    const int cl = lane & 15, r0q = (lane >> 4) * 4;
#pragma unroll
    for (int mi = 0; mi < 2; mi++)
#pragma unroll
      for (int nt = 0; nt < 8; nt++)
#pragma unroll
        for (int reg = 0; reg < 4; reg++) {
          int i = (w * 2 + mi) * 16 + r0q + reg;
          int j = nt * 16 + cl;
          float s = S[mi][nt][reg];
          float aij = (j <= i) ? fmaf(s, fmaf(s, 0.03125f, 0.25f), 1.0f) : 0.0f;
          U[8192 + ((i >> 4) * 4 + (j >> 5)) * 512 +
            (((j >> 3) & 3) * 16 + (i & 15)) * 8 + (j & 7)] = (short)f2bf(aij);
        }
  }
  // ---- stage Vp (coalesced loads + LDS scatter) ----
  stage_Vp(qkvb, row0, h, tid, U + 24576);
  __syncthreads();

  // ---- phase 2: Y = A · Vp ----
  f32x4 Y[2][5] = {};
#pragma unroll
  for (int kc = 0; kc < 4; kc++) {
    bf16x8 a2[2];
#pragma unroll
    for (int mi = 0; mi < 2; mi++)
      a2[mi] = *(const bf16x8*)(U + 8192 + ((w * 2 + mi) * 4 + kc) * 512 + lane * 8);
#pragma unroll
    for (int nt = 0; nt < 5; nt++) {
      bf16x8 b2 = *(const bf16x8*)(U + 24576 + (nt * 4 + kc) * 512 + lane * 8);
#pragma unroll
      for (int mi = 0; mi < 2; mi++)
        Y[mi][nt] = __builtin_amdgcn_mfma_f32_16x16x32_bf16(a2[mi], b2, Y[mi][nt], 0, 0, 0);
    }
  }
  __syncthreads();  // phase-2 reads done; U[0..36863] free for Qf

  // ---- Qf gen: thread-owns-row, q in VGPRs, one mul per feature ----
  {
    float qv[16], cq[16];
#pragma unroll
    for (int j = 0; j < 8; j++) {
      qv[j] = bf2f((unsigned short)qa[j]);
      qv[8 + j] = bf2f((unsigned short)qb[j]);
    }
#pragma unroll
    for (int j = 0; j < 16; j++) cq[j] = C2 * qv[j];
    unsigned short* qbase = Uu + (qrow >> 4) * 512 + (qrow & 15) * 8;
    if (shalf == 0) {
#pragma unroll
      for (int vk = 0; vk < 18; vk++) {
        bf16x8 v8;
#pragma unroll
        for (int j = 0; j < 8; j++) {
          int f = vk * 8 + j;
          float qf;
          if (f == 0) qf = 1.0f;
          else if (f < 17) qf = 0.5f * qv[f - 1];
          else { int ix = f - 17; qf = cq[ix >> 4] * qv[ix & 15]; }
          v8[j] = (short)f2bf(qf);
        }
        *(bf16x8*)(qbase + (vk >> 2) * 4096 + (vk & 3) * 128) = v8;
      }
    } else {
#pragma unroll
      for (int vk = 18; vk < 36; vk++) {
        bf16x8 v8;
#pragma unroll
        for (int j = 0; j < 8; j++) {
          int f = vk * 8 + j;
          float qf;
          if (f < FDIM) { int ix = f - 17; qf = cq[ix >> 4] * qv[ix & 15]; }
          else qf = 0.0f;
          v8[j] = (short)f2bf(qf);
        }
        *(bf16x8*)(qbase + (vk >> 2) * 4096 + (vk & 3) * 128) = v8;
      }
    }
  }
  __syncthreads();  // Qf complete; phase 3 is barrier-free from here

  // ---- phase 3: Y += Qf · [P|u]; B-fragments DIRECT from global PG ----
  const unsigned short* pgl = PG + ((size_t)bh * NCH + c) * 45 * 512 + lane * 8;
#pragma unroll
  for (int ft = 0; ft < 9; ft++) {
    bf16x8 b3[5];
#pragma unroll
    for (int nt = 0; nt < 5; nt++)
      b3[nt] = *(const bf16x8*)(pgl + (ft * 5 + nt) * 512);
    bf16x8 a3[2];
#pragma unroll
    for (int mi = 0; mi < 2; mi++)
      a3[mi] = *(const bf16x8*)(U + ft * 4096 + (w * 2 + mi) * 512 + lane * 8);
#pragma unroll
    for (int nt = 0; nt < 5; nt++)
#pragma unroll
      for (int mi = 0; mi < 2; mi++)
        Y[mi][nt] = __builtin_amdgcn_mfma_f32_16x16x32_bf16(a3[mi], b3[nt], Y[mi][nt], 0, 0, 0);
  }

  // ---- epilogue: den from ones column (nt=4, col 0), scale, store bf16 ----
  const int cl = lane & 15, r0q = (lane >> 4) * 4;
  if (cl == 0) {
#pragma unroll
    for (int mi = 0; mi < 2; mi++)
#pragma unroll
      for (int reg = 0; reg < 4; reg++)
        denL[(w * 2 + mi) * 16 + r0q + reg] = Y[mi][4][reg];
  }
  __syncthreads();
#pragma unroll
  for (int mi = 0; mi < 2; mi++) {
    float invd[4];
#pragma unroll
    for (int reg = 0; reg < 4; reg++)
      invd[reg] = 1.0f / (denL[(w * 2 + mi) * 16 + r0q + reg] + 1e-12f);
#pragma unroll
    for (int nt = 0; nt < 4; nt++)
#pragma unroll
      for (int reg = 0; reg < 4; reg++) {
        int i = (w * 2 + mi) * 16 + r0q + reg;
        int e = nt * 16 + cl;
        ybuf[(size_t)(row0 + i) * (NH * DV) + h * DV + e] =
            f2bf(Y[mi][nt][reg] * invd[reg]);
      }
  }
}

// ---------------------------------------------------------------------------
extern "C" void kernel_launch(void* const* d_in, const int* in_sizes, int n_in,
                              void* d_out, int out_size, void* d_ws, size_t ws_size,
                              hipStream_t stream) {
  const float* hs = (const float*)d_in[0];
  const float* Wq = (const float*)d_in[1];
  const float* Wk = (const float*)d_in[2];
  const float* Wv = (const float*)d_in[3];
  const float* Wo = (const float*)d_in[4];
  float* out = (float*)d_out;

  // workspace layout (~73 MB)
  unsigned short* qkvb  = (unsigned short*)d_ws;            // 4096 x 1536 bf16 (q|k|v)
  unsigned short* Sfrag = qkvb + (size_t)ROWS * QKVW;       // 512 x 45 x 512 bf16
  unsigned short* PG    = Sfrag + (size_t)NBC * 45 * 512;   // 512 x 45 x 512 bf16
  unsigned short* hsb   = PG + (size_t)NBC * 45 * 512;      // 4096 x 1024 bf16
  unsigned short* yb    = hsb;  // alias: hsb dead after projection GEMM
  unsigned short* wqt   = hsb + (size_t)ROWS * DMODEL;      // 256 x 1024 bf16
  unsigned short* wkt   = wqt + (size_t)(NH * DQK) * DMODEL;
  unsigned short* wvt   = wkt + (size_t)(NH * DQK) * DMODEL; // contiguous -> 1536x1024
  unsigned short* wot   = wvt + (size_t)(NH * DV) * DMODEL;  // 1024 x 1024 bf16

  // fused casts + transposes (one launch)
  prep<<<dim3(32, 32, 5), 256, 0, stream>>>(hs, Wq, Wk, Wv, Wo, hsb, wqt, wkt, wvt, wot);

  // fused q|k|v projection (MFMA, bf16 out, N=1536): 384 blocks, 128^2 tile
  gemm_pipe<unsigned short><<<dim3(QKVW / 128, ROWS / 128), 256, 0, stream>>>(
      hsb, wqt, qkvb, ROWS, QKVW, DMODEL);

  // chunked causal linear attention
  chunk_sums_mfma<<<dim3(NCH, NBH), 256, 0, stream>>>(qkvb, Sfrag);
  prefix_scan_frag<<<dim3(45, NBH), 64, 0, stream>>>(Sfrag, PG);
  attn_mfma<<<dim3(NCH, NBH), 256, 0, stream>>>(qkvb, PG, yb);

  // output projection (MFMA, fp32 out): 256 blocks = 1/CU, 128^2 tile
  gemm_pipe<float><<<dim3(DMODEL / 128, ROWS / 128), 256, 0, stream>>>(
      yb, wot, out, ROWS, DMODEL, DMODEL);
}